// Round 9
// baseline (154.163 us; speedup 1.0000x reference)
//
#include <hip/hip_runtime.h>

#define NROWS 131072
#define DDIM  64
#define KCTR  512
#define OUT_W 577                 /* 1 + 64 + 512 */
#define RPB   16                  /* rows per tile */
#define NTILES (NROWS / RPB)      /* 8192 */
#define GRID 1024                 /* 4 blocks/CU x 256 CU, persistent */
#define ROUNDS (NTILES / GRID)    /* 8, exact */
#define K_HALF_LN2 0.34657359027997264f   /* 0.5*ln(2) */

typedef __attribute__((ext_vector_type(8))) short bfrag8;
typedef __attribute__((ext_vector_type(4))) float f32x4;

// 16B vector store with only 4B alignment (out rows are 2308B-strided).
struct __attribute__((packed, aligned(4))) F4a4 { f32x4 v; };

__device__ __forceinline__ short f2bf(float f) {
    union { float f; unsigned u; } v; v.f = f;
    return (short)((v.u + 0x8000u) >> 16);   // round-to-nearest
}

// __syncthreads minus the vmcnt(0) drain: waits only LDS ops, leaves global
// stores/loads in flight across the barrier.
__device__ __forceinline__ void lds_barrier() {
    asm volatile("s_waitcnt lgkmcnt(0)" ::: "memory");
    __builtin_amdgcn_s_barrier();
    __builtin_amdgcn_sched_barrier(0);
}

__global__ __launch_bounds__(256, 4) void dicrbf_mfma(
    const float* __restrict__ data,
    const float* __restrict__ centers,
    float* __restrict__ out)
{
    __shared__ short s_dbf[RPB][72];   // bf16 data tile, 2304 B (R6 layout)
    __shared__ float s_xsq[RPB];
    __shared__ float s_cnorm[KCTR];    // 2 KB
    // total ~4.4 KB -> LDS never the occupancy limiter

    const int t    = threadIdx.x;
    const int lane = t & 63;
    const int wid  = t >> 6;
    const int l15  = lane & 15;
    const int lhi  = lane >> 4;
    const int cbase = wid * 128;          // this wave's 128 centers

    // ---- Prologue A: center norms (f32 exact) -> LDS ----
    for (int k = t; k < KCTR; k += 256) {
        const f32x4* c4 = reinterpret_cast<const f32x4*>(centers + (size_t)k * DDIM);
        float s = 0.f;
#pragma unroll
        for (int i = 0; i < DDIM / 4; ++i) {
            f32x4 u = c4[i];
            s += u[0]*u[0] + u[1]*u[1] + u[2]*u[2] + u[3]*u[3];
        }
        s_cnorm[k] = s;
    }

    // ---- Prologue B: A-fragments = bf16(-2*center) -> registers ----
    bfrag8 afr[8][2];
#pragma unroll
    for (int mf = 0; mf < 8; ++mf) {
        const float* cp = centers + (size_t)(cbase + mf * 16 + l15) * DDIM + lhi * 8;
#pragma unroll
        for (int ks = 0; ks < 2; ++ks) {
            const f32x4 u0 = *reinterpret_cast<const f32x4*>(cp + ks * 32);
            const f32x4 u1 = *reinterpret_cast<const f32x4*>(cp + ks * 32 + 4);
            bfrag8 fr;
            fr[0] = f2bf(-2.f*u0[0]); fr[1] = f2bf(-2.f*u0[1]);
            fr[2] = f2bf(-2.f*u0[2]); fr[3] = f2bf(-2.f*u0[3]);
            fr[4] = f2bf(-2.f*u1[0]); fr[5] = f2bf(-2.f*u1[1]);
            fr[6] = f2bf(-2.f*u1[2]); fr[7] = f2bf(-2.f*u1[3]);
            afr[mf][ks] = fr;
        }
    }
    __syncthreads();   // one-time full barrier; cnorm visible

    // per-lane center norms (4 consecutive centers per mf) -> registers
    f32x4 cnr[8];
#pragma unroll
    for (int mf = 0; mf < 8; ++mf)
        cnr[mf] = *reinterpret_cast<const f32x4*>(&s_cnorm[cbase + mf * 16 + lhi * 4]);

    // ---- Persistent tile loop: 2 lds_barriers/round, no vmcnt drains ----
    const int r  = t >> 4;      // row within tile
    const int jj = t & 15;      // 4-float chunk within row

    size_t tile = blockIdx.x;
    f32x4 v = *reinterpret_cast<const f32x4*>(data + (tile * RPB + r) * DDIM + jj * 4);

    for (int round = 0; round < ROUNDS; ++round, tile += GRID) {
        // P1: xsq reduce + bf16 tile + DIRECT passthrough stores; prefetch next
        float s = v[0]*v[0] + v[1]*v[1] + v[2]*v[2] + v[3]*v[3];
        s += __shfl_xor(s, 1);
        s += __shfl_xor(s, 2);
        s += __shfl_xor(s, 4);
        s += __shfl_xor(s, 8);
        if (jj == 0) s_xsq[r] = s;

        short b4[4] = { f2bf(v[0]), f2bf(v[1]), f2bf(v[2]), f2bf(v[3]) };
        *reinterpret_cast<uint2*>(&s_dbf[r][jj * 4]) =
            *reinterpret_cast<const uint2*>(b4);

        float* orow = out + (tile * RPB + r) * (size_t)OUT_W;
        reinterpret_cast<F4a4*>(orow + 1 + jj * 4)->v = v;
        if (jj == 0) orow[0] = 1.0f;

        if (round + 1 < ROUNDS)
            v = *reinterpret_cast<const f32x4*>(
                data + ((tile + GRID) * RPB + r) * DDIM + jj * 4);

        lds_barrier();   // (B1) dbf/xsq visible

        // P2: MFMA (C-init = xsq + cn) + direct 16B rbf stores
        const bfrag8 b0 = *reinterpret_cast<const bfrag8*>(&s_dbf[l15][lhi * 8]);
        const bfrag8 b1 = *reinterpret_cast<const bfrag8*>(&s_dbf[l15][32 + lhi * 8]);
        const float xsq = s_xsq[l15];

        float* orbf = out + (tile * RPB + l15) * (size_t)OUT_W + 1 + DDIM + cbase + lhi * 4;

#pragma unroll
        for (int mf = 0; mf < 8; ++mf) {
            f32x4 acc;
#pragma unroll
            for (int k = 0; k < 4; ++k) acc[k] = xsq + cnr[mf][k];
            acc = __builtin_amdgcn_mfma_f32_16x16x32_bf16(afr[mf][0], b0, acc, 0, 0, 0);
            acc = __builtin_amdgcn_mfma_f32_16x16x32_bf16(afr[mf][1], b1, acc, 0, 0, 0);

            f32x4 w;
#pragma unroll
            for (int k = 0; k < 4; ++k) {
                const float d2 = fmaxf(acc[k], 1e-30f);   // clamps negatives; ~0 stays ~0
                w[k] = (K_HALF_LN2 * d2) * __log2f(d2);
            }
            reinterpret_cast<F4a4*>(orbf + mf * 16)->v = w;
        }

        lds_barrier();   // (B2) dbf reads retired; safe to overwrite next round
    }
}

extern "C" void kernel_launch(void* const* d_in, const int* in_sizes, int n_in,
                              void* d_out, int out_size, void* d_ws, size_t ws_size,
                              hipStream_t stream) {
    const float* data    = (const float*)d_in[0];
    const float* centers = (const float*)d_in[1];
    float* out = (float*)d_out;

    hipLaunchKernelGGL(dicrbf_mfma, dim3(GRID), dim3(256), 0, stream,
                       data, centers, out);
}

// Round 10
// 115.184 us; speedup vs baseline: 1.3384x; 1.3384x over previous
//
#include <hip/hip_runtime.h>

#define NROWS 131072
#define DDIM  64
#define KCTR  512
#define OUT_W 577                 /* 1 + 64 + 512 */
#define RPB   8                   /* rows per tile */
#define NTILES (NROWS / RPB)      /* 16384 */
#define SPAN_F32 (RPB * OUT_W)    /* 4616 floats = 18464 B */
#define SPAN_V4  (SPAN_F32 / 4)   /* 1154 = 4*256 + 130 */
#define GRID 768                  /* 3 blocks/CU x 256 CU, persistent */
#define K_HALF_LN2 0.34657359027997264f   /* 0.5*ln(2) */

typedef __attribute__((ext_vector_type(8))) short bfrag8;
typedef __attribute__((ext_vector_type(4))) float f32x4;

__device__ __forceinline__ short f2bf(float f) {
    union { float f; unsigned u; } v; v.f = f;
    return (short)((v.u + 0x8000u) >> 16);   // round-to-nearest
}

// __syncthreads minus the vmcnt(0) drain: waits only LDS ops, leaves global
// stores/loads in flight across the barrier.
__device__ __forceinline__ void lds_barrier() {
    asm volatile("s_waitcnt lgkmcnt(0)" ::: "memory");
    __builtin_amdgcn_s_barrier();
    __builtin_amdgcn_sched_barrier(0);
}

__global__ __launch_bounds__(256, 3) void dicrbf_mfma(
    const float* __restrict__ data,
    const float* __restrict__ centers,
    float* __restrict__ out)
{
    __shared__ __align__(16) float s_span[2][SPAN_F32];  // 36928 B double-buffered
    __shared__ short s_dbf[16][72];                      // bf16 tile; rows 8..15 zero
    __shared__ float s_xsq[16];                          // [8..15] zero
    __shared__ float s_cnorm[KCTR];                      // 2 KB
    // total ~41.3 KB -> 3 blocks/CU

    const int t    = threadIdx.x;
    const int lane = t & 63;
    const int wid  = t >> 6;
    const int l15  = lane & 15;
    const int lhi  = lane >> 4;
    const int cbase = wid * 128;          // this wave's 128 centers

    // ---- Prologue A: center norms (f32 exact) -> LDS ----
    for (int k = t; k < KCTR; k += 256) {
        const f32x4* c4 = reinterpret_cast<const f32x4*>(centers + (size_t)k * DDIM);
        float s = 0.f;
#pragma unroll
        for (int i = 0; i < DDIM / 4; ++i) {
            f32x4 u = c4[i];
            s += u[0]*u[0] + u[1]*u[1] + u[2]*u[2] + u[3]*u[3];
        }
        s_cnorm[k] = s;
    }

    // zero-fill dbf rows 8..15 and xsq[8..15] (read by l15>=8 lanes, discarded)
    if (t < 128) {
        uint2 z; z.x = 0; z.y = 0;
        *reinterpret_cast<uint2*>(&s_dbf[8 + (t >> 4)][(t & 15) * 4]) = z;
    }
    if (t >= 8 && t < 16) s_xsq[t] = 0.f;

    // ---- Prologue B: A-fragments = bf16(-2*center) -> registers ----
    bfrag8 afr[8][2];
#pragma unroll
    for (int mf = 0; mf < 8; ++mf) {
        const float* cp = centers + (size_t)(cbase + mf * 16 + l15) * DDIM + lhi * 8;
#pragma unroll
        for (int ks = 0; ks < 2; ++ks) {
            const f32x4 u0 = *reinterpret_cast<const f32x4*>(cp + ks * 32);
            const f32x4 u1 = *reinterpret_cast<const f32x4*>(cp + ks * 32 + 4);
            bfrag8 fr;
            fr[0] = f2bf(-2.f*u0[0]); fr[1] = f2bf(-2.f*u0[1]);
            fr[2] = f2bf(-2.f*u0[2]); fr[3] = f2bf(-2.f*u0[3]);
            fr[4] = f2bf(-2.f*u1[0]); fr[5] = f2bf(-2.f*u1[1]);
            fr[6] = f2bf(-2.f*u1[2]); fr[7] = f2bf(-2.f*u1[3]);
            afr[mf][ks] = fr;
        }
    }
    __syncthreads();   // one-time full barrier; cnorm/zero-fills visible

    // per-lane center norms (4 consecutive centers per mf) -> registers
    f32x4 cnr[8];
#pragma unroll
    for (int mf = 0; mf < 8; ++mf)
        cnr[mf] = *reinterpret_cast<const f32x4*>(&s_cnorm[cbase + mf * 16 + lhi * 4]);

    // ---- Persistent tile loop (R6 schedule): P1 B1 P2 B2 P3, dbuf span ----
    // P1 mapping: tile = contiguous 512 floats of data; threads 0..127 take one
    // f32x4 each: row r = t>>4 (0..7), chunk c4 = t&15.
    const int r  = t >> 4;
    const int c4 = t & 15;

    size_t tile = blockIdx.x;
    f32x4 v;
    if (t < 128) v = *reinterpret_cast<const f32x4*>(data + tile * (RPB * DDIM) + t * 4);

    int p = 0;
    for (; tile < NTILES; tile += GRID, p ^= 1) {
        float* span = s_span[p];

        if (t < 128) {
            // xsq reduce over the 16-thread row group
            float s = v[0]*v[0] + v[1]*v[1] + v[2]*v[2] + v[3]*v[3];
            s += __shfl_xor(s, 1);
            s += __shfl_xor(s, 2);
            s += __shfl_xor(s, 4);
            s += __shfl_xor(s, 8);
            if (c4 == 0) { s_xsq[r] = s; span[r * OUT_W] = 1.0f; }

            // passthrough into span (cols 1..64)
            float* spv = &span[r * OUT_W + 1 + c4 * 4];
            spv[0] = v[0]; spv[1] = v[1]; spv[2] = v[2]; spv[3] = v[3];

            // bf16 tile
            short b4[4] = { f2bf(v[0]), f2bf(v[1]), f2bf(v[2]), f2bf(v[3]) };
            *reinterpret_cast<uint2*>(&s_dbf[r][c4 * 4]) =
                *reinterpret_cast<const uint2*>(b4);

            // prefetch next tile
            if (tile + GRID < NTILES)
                v = *reinterpret_cast<const f32x4*>(
                    data + (tile + GRID) * (RPB * DDIM) + t * 4);
        }

        lds_barrier();   // (B1) dbf/xsq/passthrough visible

        // P2: MFMA (C-init = xsq + cn) + epilogue into span, rows l15<8 only
        const bfrag8 b0 = *reinterpret_cast<const bfrag8*>(&s_dbf[l15][lhi * 8]);
        const bfrag8 b1 = *reinterpret_cast<const bfrag8*>(&s_dbf[l15][32 + lhi * 8]);
        const float xsq = s_xsq[l15];

#pragma unroll
        for (int mf = 0; mf < 8; ++mf) {
            f32x4 acc;
#pragma unroll
            for (int k = 0; k < 4; ++k) acc[k] = xsq + cnr[mf][k];
            acc = __builtin_amdgcn_mfma_f32_16x16x32_bf16(afr[mf][0], b0, acc, 0, 0, 0);
            acc = __builtin_amdgcn_mfma_f32_16x16x32_bf16(afr[mf][1], b1, acc, 0, 0, 0);

            if (l15 < 8) {
                float* sp = &span[l15 * OUT_W + 1 + DDIM + cbase + mf * 16 + lhi * 4];
#pragma unroll
                for (int k = 0; k < 4; ++k) {
                    const float d2 = fmaxf(acc[k], 1e-30f);
                    sp[k] = (K_HALF_LN2 * d2) * __log2f(d2);
                }
            }
        }

        lds_barrier();   // (B2) span complete; dbf reads retired

        // P3: stream span out — aligned, fully coalesced, each line once
        const f32x4* sp4 = reinterpret_cast<const f32x4*>(span);
        f32x4* o4 = reinterpret_cast<f32x4*>(out) + tile * (size_t)SPAN_V4;
#pragma unroll
        for (int i = 0; i < 4; ++i)
            o4[t + i * 256] = sp4[t + i * 256];
        if (t < SPAN_V4 - 4 * 256)
            o4[t + 4 * 256] = sp4[t + 4 * 256];
    }
}

extern "C" void kernel_launch(void* const* d_in, const int* in_sizes, int n_in,
                              void* d_out, int out_size, void* d_ws, size_t ws_size,
                              hipStream_t stream) {
    const float* data    = (const float*)d_in[0];
    const float* centers = (const float*)d_in[1];
    float* out = (float*)d_out;

    hipLaunchKernelGGL(dicrbf_mfma, dim3(GRID), dim3(256), 0, stream,
                       data, centers, out);
}

// Round 11
// 91.234 us; speedup vs baseline: 1.6898x; 1.2625x over previous
//
#include <hip/hip_runtime.h>

#define NROWS 131072
#define DDIM  64
#define KCTR  512
#define OUT_W 577                 /* 1 + 64 + 512 */
#define RPB   16                  /* rows per tile */
#define NTILES (NROWS / RPB)      /* 8192 */
#define SPAN_F32 (RPB * OUT_W)    /* 9232 floats = 36928 B */
#define SPAN_V4  (SPAN_F32 / 4)   /* 2308 = 9*256 + 4 */
#define GRID 768                  /* 3 blocks/CU x 256 CU, persistent */
#define K_HALF_LN2 0.34657359027997264f   /* 0.5*ln(2) */

typedef __attribute__((ext_vector_type(8))) short bfrag8;
typedef __attribute__((ext_vector_type(4))) float f32x4;

__device__ __forceinline__ short f2bf(float f) {
    union { float f; unsigned u; } v; v.f = f;
    return (short)((v.u + 0x8000u) >> 16);   // round-to-nearest
}

// __syncthreads minus the vmcnt(0) drain: waits only LDS ops, leaves global
// stores/loads in flight across the barrier.
__device__ __forceinline__ void lds_barrier() {
    asm volatile("s_waitcnt lgkmcnt(0)" ::: "memory");
    __builtin_amdgcn_s_barrier();
    __builtin_amdgcn_sched_barrier(0);
}

__global__ __launch_bounds__(256, 3) void dicrbf_mfma(
    const float* __restrict__ data,
    const float* __restrict__ centers,
    float* __restrict__ out)
{
    __shared__ __align__(16) float s_span[SPAN_F32];   // 36928 B, single buffer
    __shared__ short s_dbf[RPB][72];                   // bf16 data tile, 2304 B
    __shared__ float s_xsq[RPB];
    __shared__ float s_cnorm[KCTR];                    // 2 KB
    // total 41344 B -> 3 blocks/CU

    const int t    = threadIdx.x;
    const int lane = t & 63;
    const int wid  = t >> 6;
    const int l15  = lane & 15;
    const int lhi  = lane >> 4;
    const int cbase = wid * 128;          // this wave's 128 centers

    // ---- Prologue A: center norms (f32 exact) -> LDS ----
    for (int k = t; k < KCTR; k += 256) {
        const f32x4* c4 = reinterpret_cast<const f32x4*>(centers + (size_t)k * DDIM);
        float s = 0.f;
#pragma unroll
        for (int i = 0; i < DDIM / 4; ++i) {
            f32x4 u = c4[i];
            s += u[0]*u[0] + u[1]*u[1] + u[2]*u[2] + u[3]*u[3];
        }
        s_cnorm[k] = s;
    }

    // ---- Prologue B: A-fragments = bf16(-2*center) -> registers ----
    bfrag8 afr[8][2];
#pragma unroll
    for (int mf = 0; mf < 8; ++mf) {
        const float* cp = centers + (size_t)(cbase + mf * 16 + l15) * DDIM + lhi * 8;
#pragma unroll
        for (int ks = 0; ks < 2; ++ks) {
            const f32x4 u0 = *reinterpret_cast<const f32x4*>(cp + ks * 32);
            const f32x4 u1 = *reinterpret_cast<const f32x4*>(cp + ks * 32 + 4);
            bfrag8 fr;
            fr[0] = f2bf(-2.f*u0[0]); fr[1] = f2bf(-2.f*u0[1]);
            fr[2] = f2bf(-2.f*u0[2]); fr[3] = f2bf(-2.f*u0[3]);
            fr[4] = f2bf(-2.f*u1[0]); fr[5] = f2bf(-2.f*u1[1]);
            fr[6] = f2bf(-2.f*u1[2]); fr[7] = f2bf(-2.f*u1[3]);
            afr[mf][ks] = fr;
        }
    }
    __syncthreads();   // one-time full barrier; cnorm visible

    // per-lane center norms (4 consecutive centers per mf) -> registers
    f32x4 cnr[8];
#pragma unroll
    for (int mf = 0; mf < 8; ++mf)
        cnr[mf] = *reinterpret_cast<const f32x4*>(&s_cnorm[cbase + mf * 16 + lhi * 4]);

    // ---- Persistent tile loop: single span, 2 lds_barriers/round ----
    // Race-freedom: B1 guarantees every wave's P3(r) span ds_reads retired
    // (per-wave lgkmcnt(0) precedes barrier arrival) before any P2(r+1) write.
    const int r  = t >> 4;      // row within tile
    const int jj = t & 15;      // 4-float chunk within row

    size_t tile = blockIdx.x;
    f32x4 v = *reinterpret_cast<const f32x4*>(data + (tile * RPB + r) * DDIM + jj * 4);

    for (; tile < NTILES; tile += GRID) {
        // P1: xsq reduce + bf16 tile from cur; prefetch next into v
        const f32x4 cur = v;
        float s = cur[0]*cur[0] + cur[1]*cur[1] + cur[2]*cur[2] + cur[3]*cur[3];
        s += __shfl_xor(s, 1);
        s += __shfl_xor(s, 2);
        s += __shfl_xor(s, 4);
        s += __shfl_xor(s, 8);
        if (jj == 0) s_xsq[r] = s;

        short b4[4] = { f2bf(cur[0]), f2bf(cur[1]), f2bf(cur[2]), f2bf(cur[3]) };
        *reinterpret_cast<uint2*>(&s_dbf[r][jj * 4]) =
            *reinterpret_cast<const uint2*>(b4);

        if (tile + GRID < NTILES)
            v = *reinterpret_cast<const f32x4*>(
                data + ((tile + GRID) * RPB + r) * DDIM + jj * 4);

        lds_barrier();   // (B1) dbf/xsq visible; prev-round span reads retired

        // P2a: passthrough into span (cols 0..64) from held registers
        float* spv = &s_span[r * OUT_W + 1 + jj * 4];
        spv[0] = cur[0]; spv[1] = cur[1]; spv[2] = cur[2]; spv[3] = cur[3];
        if (jj == 0) s_span[r * OUT_W] = 1.0f;

        // P2b: MFMA (C-init = xsq + cn) + epilogue into span
        const bfrag8 b0 = *reinterpret_cast<const bfrag8*>(&s_dbf[l15][lhi * 8]);
        const bfrag8 b1 = *reinterpret_cast<const bfrag8*>(&s_dbf[l15][32 + lhi * 8]);
        const float xsq = s_xsq[l15];

#pragma unroll
        for (int mf = 0; mf < 8; ++mf) {
            f32x4 acc;
#pragma unroll
            for (int k = 0; k < 4; ++k) acc[k] = xsq + cnr[mf][k];
            acc = __builtin_amdgcn_mfma_f32_16x16x32_bf16(afr[mf][0], b0, acc, 0, 0, 0);
            acc = __builtin_amdgcn_mfma_f32_16x16x32_bf16(afr[mf][1], b1, acc, 0, 0, 0);

            float* sp = &s_span[l15 * OUT_W + 1 + DDIM + cbase + mf * 16 + lhi * 4];
#pragma unroll
            for (int k = 0; k < 4; ++k) {
                const float d2 = fmaxf(acc[k], 1e-30f);   // clamps negatives; ~0 stays ~0
                sp[k] = (K_HALF_LN2 * d2) * __log2f(d2);
            }
        }

        lds_barrier();   // (B2) span fully written

        // P3: stream span out — aligned, fully coalesced, each line once
        const f32x4* sp4 = reinterpret_cast<const f32x4*>(s_span);
        f32x4* o4 = reinterpret_cast<f32x4*>(out) + tile * (size_t)SPAN_V4;
#pragma unroll
        for (int i = 0; i < 9; ++i)
            o4[t + i * 256] = sp4[t + i * 256];
        if (t < 4) o4[2304 + t] = sp4[2304 + t];
    }
}

extern "C" void kernel_launch(void* const* d_in, const int* in_sizes, int n_in,
                              void* d_out, int out_size, void* d_ws, size_t ws_size,
                              hipStream_t stream) {
    const float* data    = (const float*)d_in[0];
    const float* centers = (const float*)d_in[1];
    float* out = (float*)d_out;

    hipLaunchKernelGGL(dicrbf_mfma, dim3(GRID), dim3(256), 0, stream,
                       data, centers, out);
}

// Round 12
// 87.355 us; speedup vs baseline: 1.7648x; 1.0444x over previous
//
#include <hip/hip_runtime.h>

#define NROWS 131072
#define DDIM  64
#define KCTR  512
#define OUT_W 577                 /* 1 + 64 + 512 */
#define RPB   16                  /* rows per tile */
#define NTILES (NROWS / RPB)      /* 8192 */
#define SPAN_F32 (RPB * OUT_W)    /* 9232 floats = 36928 B */
#define SPAN_V4  (SPAN_F32 / 4)   /* 2308 = 9*256 + 4 */
#define GRID 512                  /* 2 blocks/CU x 256 CU, persistent */
#define ROUNDS (NTILES / GRID)    /* 16, exact */
#define K_HALF_LN2 0.34657359027997264f   /* 0.5*ln(2) */

typedef __attribute__((ext_vector_type(8))) short bfrag8;
typedef __attribute__((ext_vector_type(4))) float f32x4;

__device__ __forceinline__ short f2bf(float f) {
    union { float f; unsigned u; } v; v.f = f;
    return (short)((v.u + 0x8000u) >> 16);   // round-to-nearest
}

// __syncthreads minus the vmcnt(0) drain: waits only LDS ops, leaves global
// stores/loads in flight across the barrier.
__device__ __forceinline__ void lds_barrier() {
    asm volatile("s_waitcnt lgkmcnt(0)" ::: "memory");
    __builtin_amdgcn_s_barrier();
    __builtin_amdgcn_sched_barrier(0);
}

__global__ __launch_bounds__(256, 2) void dicrbf_mfma(
    const float* __restrict__ data,
    const float* __restrict__ centers,
    float* __restrict__ out)
{
    __shared__ __align__(16) float s_span[2][SPAN_F32];  // 73856 B double-buffered
    __shared__ short s_dbf[RPB][72];                     // bf16 data tile
    __shared__ float s_xsq[RPB];
    __shared__ float s_cnorm[KCTR];

    const int t    = threadIdx.x;
    const int lane = t & 63;
    const int wid  = t >> 6;
    const int l15  = lane & 15;
    const int lhi  = lane >> 4;
    const int cbase = wid * 128;          // this wave's 128 centers

    // ---- Prologue A: center norms (f32 exact) -> LDS ----
    for (int k = t; k < KCTR; k += 256) {
        const f32x4* c4 = reinterpret_cast<const f32x4*>(centers + (size_t)k * DDIM);
        float s = 0.f;
#pragma unroll
        for (int i = 0; i < DDIM / 4; ++i) {
            f32x4 u = c4[i];
            s += u[0]*u[0] + u[1]*u[1] + u[2]*u[2] + u[3]*u[3];
        }
        s_cnorm[k] = s;
    }

    // ---- Prologue B: A-fragments = bf16(-2*center) -> registers ----
    bfrag8 afr[8][2];
#pragma unroll
    for (int mf = 0; mf < 8; ++mf) {
        const float* cp = centers + (size_t)(cbase + mf * 16 + l15) * DDIM + lhi * 8;
#pragma unroll
        for (int ks = 0; ks < 2; ++ks) {
            const f32x4 u0 = *reinterpret_cast<const f32x4*>(cp + ks * 32);
            const f32x4 u1 = *reinterpret_cast<const f32x4*>(cp + ks * 32 + 4);
            bfrag8 fr;
            fr[0] = f2bf(-2.f*u0[0]); fr[1] = f2bf(-2.f*u0[1]);
            fr[2] = f2bf(-2.f*u0[2]); fr[3] = f2bf(-2.f*u0[3]);
            fr[4] = f2bf(-2.f*u1[0]); fr[5] = f2bf(-2.f*u1[1]);
            fr[6] = f2bf(-2.f*u1[2]); fr[7] = f2bf(-2.f*u1[3]);
            afr[mf][ks] = fr;
        }
    }
    __syncthreads();   // one-time full barrier; cnorm visible

    // per-lane center norms (4 consecutive centers per mf) -> registers
    f32x4 cnr[8];
#pragma unroll
    for (int mf = 0; mf < 8; ++mf)
        cnr[mf] = *reinterpret_cast<const f32x4*>(&s_cnorm[cbase + mf * 16 + lhi * 4]);

    // ---- Persistent tile loop: dbuf span, 2 lds_barriers/round ----
    const int r  = t >> 4;      // row within tile
    const int jj = t & 15;      // 4-float chunk within row

    size_t tile = blockIdx.x;
    f32x4 v = __builtin_nontemporal_load(
        reinterpret_cast<const f32x4*>(data + (tile * RPB + r) * DDIM + jj * 4));

    int p = 0;
    for (int round = 0; round < ROUNDS; ++round, tile += GRID, p ^= 1) {
        float* span = s_span[p];

        // P1: xsq reduce + passthrough into span + bf16 tile; prefetch next
        float s = v[0]*v[0] + v[1]*v[1] + v[2]*v[2] + v[3]*v[3];
        s += __shfl_xor(s, 1);
        s += __shfl_xor(s, 2);
        s += __shfl_xor(s, 4);
        s += __shfl_xor(s, 8);
        if (jj == 0) { s_xsq[r] = s; span[r * OUT_W] = 1.0f; }

        float* spv = &span[r * OUT_W + 1 + jj * 4];
        spv[0] = v[0]; spv[1] = v[1]; spv[2] = v[2]; spv[3] = v[3];

        short b4[4] = { f2bf(v[0]), f2bf(v[1]), f2bf(v[2]), f2bf(v[3]) };
        *reinterpret_cast<uint2*>(&s_dbf[r][jj * 4]) =
            *reinterpret_cast<const uint2*>(b4);

        if (round + 1 < ROUNDS)
            v = __builtin_nontemporal_load(reinterpret_cast<const f32x4*>(
                data + ((tile + GRID) * RPB + r) * DDIM + jj * 4));

        lds_barrier();   // (B1) dbf/xsq/passthrough visible

        // P2: MFMA (C-init = xsq + cn) + epilogue into span
        const bfrag8 b0 = *reinterpret_cast<const bfrag8*>(&s_dbf[l15][lhi * 8]);
        const bfrag8 b1 = *reinterpret_cast<const bfrag8*>(&s_dbf[l15][32 + lhi * 8]);
        const float xsq = s_xsq[l15];

#pragma unroll
        for (int mf = 0; mf < 8; ++mf) {
            f32x4 acc;
#pragma unroll
            for (int k = 0; k < 4; ++k) acc[k] = xsq + cnr[mf][k];
            acc = __builtin_amdgcn_mfma_f32_16x16x32_bf16(afr[mf][0], b0, acc, 0, 0, 0);
            acc = __builtin_amdgcn_mfma_f32_16x16x32_bf16(afr[mf][1], b1, acc, 0, 0, 0);

            float* sp = &span[l15 * OUT_W + 1 + DDIM + cbase + mf * 16 + lhi * 4];
#pragma unroll
            for (int k = 0; k < 4; ++k) {
                const float d2 = fmaxf(acc[k], 1e-30f);   // clamps negatives; ~0 stays ~0
                sp[k] = (K_HALF_LN2 * d2) * __log2f(d2);
            }
        }

        lds_barrier();   // (B2) span fully written

        // P3: stream span out — nontemporal (bypass L2 allocation), aligned,
        // fully coalesced, each 64B line written exactly once by one instr.
        const f32x4* sp4 = reinterpret_cast<const f32x4*>(span);
        f32x4* o4 = reinterpret_cast<f32x4*>(out) + tile * (size_t)SPAN_V4;
#pragma unroll
        for (int i = 0; i < 9; ++i)
            __builtin_nontemporal_store(sp4[t + i * 256], &o4[t + i * 256]);
        if (t < SPAN_V4 - 9 * 256)
            __builtin_nontemporal_store(sp4[t + 9 * 256], &o4[t + 9 * 256]);
    }
}

extern "C" void kernel_launch(void* const* d_in, const int* in_sizes, int n_in,
                              void* d_out, int out_size, void* d_ws, size_t ws_size,
                              hipStream_t stream) {
    const float* data    = (const float*)d_in[0];
    const float* centers = (const float*)d_in[1];
    float* out = (float*)d_out;

    hipLaunchKernelGGL(dicrbf_mfma, dim3(GRID), dim3(256), 0, stream,
                       data, centers, out);
}

// Round 13
// 86.314 us; speedup vs baseline: 1.7861x; 1.0121x over previous
//
#include <hip/hip_runtime.h>

#define NROWS 131072
#define DDIM  64
#define KCTR  512
#define OUT_W 577                 /* 1 + 64 + 512 */
#define RPB   16                  /* rows per tile */
#define NTILES (NROWS / RPB)      /* 8192 */
#define SPAN_F32 (RPB * OUT_W)    /* 9232 floats = 36928 B */
#define SPAN_V4  (SPAN_F32 / 4)   /* 2308 = 4*512 + 260 */
#define BLK  512                  /* threads per block, 8 waves */
#define GRID 512                  /* 2 blocks/CU x 256 CU, persistent */
#define ROUNDS (NTILES / GRID)    /* 16, exact */
#define K_HALF_LN2 0.34657359027997264f   /* 0.5*ln(2) */

typedef __attribute__((ext_vector_type(8))) short bfrag8;
typedef __attribute__((ext_vector_type(4))) float f32x4;
typedef __attribute__((ext_vector_type(2))) float f32x2;

__device__ __forceinline__ short f2bf(float f) {
    union { float f; unsigned u; } v; v.f = f;
    return (short)((v.u + 0x8000u) >> 16);   // round-to-nearest
}

// __syncthreads minus the vmcnt(0) drain: waits only LDS ops, leaves global
// stores/loads in flight across the barrier.
__device__ __forceinline__ void lds_barrier() {
    asm volatile("s_waitcnt lgkmcnt(0)" ::: "memory");
    __builtin_amdgcn_s_barrier();
    __builtin_amdgcn_sched_barrier(0);
}

__global__ __launch_bounds__(BLK, 4) void dicrbf_mfma(
    const float* __restrict__ data,
    const float* __restrict__ centers,
    float* __restrict__ out)
{
    __shared__ __align__(16) float s_span[2][SPAN_F32];  // 73856 B double-buffered
    __shared__ short s_dbf[RPB][72];                     // bf16 data tile
    __shared__ float s_xsq[RPB];
    __shared__ float s_cnorm[KCTR];
    // ~41 KB -> 2 blocks/CU at 512 threads = 16 waves/CU

    const int t    = threadIdx.x;
    const int lane = t & 63;
    const int wid  = t >> 6;          // 0..7
    const int l15  = lane & 15;
    const int lhi  = lane >> 4;
    const int cbase = wid * 64;       // this wave's 64 centers

    // ---- Prologue A: center norms (f32 exact) -> LDS, one center/thread ----
    {
        const f32x4* c4 = reinterpret_cast<const f32x4*>(centers + (size_t)t * DDIM);
        float s = 0.f;
#pragma unroll
        for (int i = 0; i < DDIM / 4; ++i) {
            f32x4 u = c4[i];
            s += u[0]*u[0] + u[1]*u[1] + u[2]*u[2] + u[3]*u[3];
        }
        s_cnorm[t] = s;
    }

    // ---- Prologue B: A-fragments = bf16(-2*center), 4 mf tiles/wave ----
    bfrag8 afr[4][2];
#pragma unroll
    for (int mf = 0; mf < 4; ++mf) {
        const float* cp = centers + (size_t)(cbase + mf * 16 + l15) * DDIM + lhi * 8;
#pragma unroll
        for (int ks = 0; ks < 2; ++ks) {
            const f32x4 u0 = *reinterpret_cast<const f32x4*>(cp + ks * 32);
            const f32x4 u1 = *reinterpret_cast<const f32x4*>(cp + ks * 32 + 4);
            bfrag8 fr;
            fr[0] = f2bf(-2.f*u0[0]); fr[1] = f2bf(-2.f*u0[1]);
            fr[2] = f2bf(-2.f*u0[2]); fr[3] = f2bf(-2.f*u0[3]);
            fr[4] = f2bf(-2.f*u1[0]); fr[5] = f2bf(-2.f*u1[1]);
            fr[6] = f2bf(-2.f*u1[2]); fr[7] = f2bf(-2.f*u1[3]);
            afr[mf][ks] = fr;
        }
    }
    __syncthreads();   // one-time full barrier; cnorm visible

    f32x4 cnr[4];
#pragma unroll
    for (int mf = 0; mf < 4; ++mf)
        cnr[mf] = *reinterpret_cast<const f32x4*>(&s_cnorm[cbase + mf * 16 + lhi * 4]);

    // ---- Persistent tile loop: dbuf span, 2 lds_barriers/round ----
    // P1 mapping: all 512 threads; row r = t>>5, f32x2 chunk jj = t&31.
    const int r  = t >> 5;
    const int jj = t & 31;

    size_t tile = blockIdx.x;
    f32x2 v = *reinterpret_cast<const f32x2*>(data + (tile * RPB + r) * DDIM + jj * 2);

    int p = 0;
    for (int round = 0; round < ROUNDS; ++round, tile += GRID, p ^= 1) {
        float* span = s_span[p];

        // P1: xsq reduce (32-lane group) + passthrough + bf16 tile; prefetch
        float s = v[0]*v[0] + v[1]*v[1];
        s += __shfl_xor(s, 1);
        s += __shfl_xor(s, 2);
        s += __shfl_xor(s, 4);
        s += __shfl_xor(s, 8);
        s += __shfl_xor(s, 16);
        if (jj == 0) { s_xsq[r] = s; span[r * OUT_W] = 1.0f; }

        float* spv = &span[r * OUT_W + 1 + jj * 2];
        spv[0] = v[0]; spv[1] = v[1];

        short b2[2] = { f2bf(v[0]), f2bf(v[1]) };
        *reinterpret_cast<unsigned*>(&s_dbf[r][jj * 2]) =
            *reinterpret_cast<const unsigned*>(b2);

        if (round + 1 < ROUNDS)
            v = *reinterpret_cast<const f32x2*>(
                data + ((tile + GRID) * RPB + r) * DDIM + jj * 2);

        lds_barrier();   // (B1) dbf/xsq/passthrough visible

        // P2: MFMA (C-init = xsq + cn) + epilogue into span; 4 mf tiles/wave
        const bfrag8 b0 = *reinterpret_cast<const bfrag8*>(&s_dbf[l15][lhi * 8]);
        const bfrag8 b1 = *reinterpret_cast<const bfrag8*>(&s_dbf[l15][32 + lhi * 8]);
        const float xsq = s_xsq[l15];

#pragma unroll
        for (int mf = 0; mf < 4; ++mf) {
            f32x4 acc;
#pragma unroll
            for (int k = 0; k < 4; ++k) acc[k] = xsq + cnr[mf][k];
            acc = __builtin_amdgcn_mfma_f32_16x16x32_bf16(afr[mf][0], b0, acc, 0, 0, 0);
            acc = __builtin_amdgcn_mfma_f32_16x16x32_bf16(afr[mf][1], b1, acc, 0, 0, 0);

            float* sp = &span[l15 * OUT_W + 1 + DDIM + cbase + mf * 16 + lhi * 4];
#pragma unroll
            for (int k = 0; k < 4; ++k) {
                const float d2 = fmaxf(acc[k], 1e-30f);   // clamps negatives; ~0 stays ~0
                sp[k] = (K_HALF_LN2 * d2) * __log2f(d2);
            }
        }

        lds_barrier();   // (B2) span fully written

        // P3: stream span out — aligned, fully coalesced, each line once
        const f32x4* sp4 = reinterpret_cast<const f32x4*>(span);
        f32x4* o4 = reinterpret_cast<f32x4*>(out) + tile * (size_t)SPAN_V4;
#pragma unroll
        for (int i = 0; i < 4; ++i)
            o4[t + i * BLK] = sp4[t + i * BLK];
        if (t < SPAN_V4 - 4 * BLK)          // 260 leftover vec4s
            o4[t + 4 * BLK] = sp4[t + 4 * BLK];
    }
}

extern "C" void kernel_launch(void* const* d_in, const int* in_sizes, int n_in,
                              void* d_out, int out_size, void* d_ws, size_t ws_size,
                              hipStream_t stream) {
    const float* data    = (const float*)d_in[0];
    const float* centers = (const float*)d_in[1];
    float* out = (float*)d_out;

    hipLaunchKernelGGL(dicrbf_mfma, dim3(GRID), dim3(BLK), 0, stream,
                       data, centers, out);
}